// Round 6
// baseline (37.322 us; speedup 1.0000x reference)
//
#include <hip/hip_runtime.h>
#include <hip/hip_bf16.h>

// out[i] = a[i, argmax_j(z[i, 3+j])], j in {0,1,2}, first-max tie-break.
// B = 4194304 rows; z row = 8 f32 (32B), a row = 3 f32 (12B).
//
// Grid-stride (2048 blocks, 4 tiles each) with double-buffered register
// prefetch: tile t+G's global loads are in flight while tile t is scattered
// to LDS and computed. All global accesses lane-contiguous. Slim staging:
// only the 3 color words of z + a in LDS (12 KB/block -> 8 blocks/CU).

#define ROWS_PER_BLOCK 512
#define NTHREADS 256
#define NBLOCKS 2048

typedef float nfloat4 __attribute__((ext_vector_type(4)));
typedef float nfloat2 __attribute__((ext_vector_type(2)));

__global__ __launch_bounds__(NTHREADS) void color_val_pipe(
    const float* __restrict__ z,
    const float* __restrict__ a,
    float* __restrict__ out,
    int ntiles)
{
    __shared__ float zc[ROWS_PER_BLOCK * 3];                // 6 KB
    __shared__ __align__(16) float as_[ROWS_PER_BLOCK * 3]; // 6 KB
    nfloat2* as2 = reinterpret_cast<nfloat2*>(as_);

    const int t = threadIdx.x;
    const int G = gridDim.x;

    nfloat4 vzA[4], vzB[4];
    nfloat2 vaA[3], vaB[3];

    auto loadT = [&](nfloat4 (&vz)[4], nfloat2 (&va)[3], int tile) {
        const nfloat4* zg = reinterpret_cast<const nfloat4*>(z)
                            + (size_t)tile * ROWS_PER_BLOCK * 2;
#pragma unroll
        for (int q = 0; q < 4; ++q)
            vz[q] = __builtin_nontemporal_load(&zg[q * NTHREADS + t]);
        const nfloat2* ag = reinterpret_cast<const nfloat2*>(a)
                            + (size_t)tile * (ROWS_PER_BLOCK * 3 / 2);
#pragma unroll
        for (int q = 0; q < 3; ++q)
            va[q] = __builtin_nontemporal_load(&ag[q * NTHREADS + t]);
    };

    auto writeLds = [&](nfloat4 (&vz)[4], nfloat2 (&va)[3]) {
#pragma unroll
        for (int q = 0; q < 4; ++q) {
            int f = q * NTHREADS + t;
            int r = f >> 1;
            int odd = f & 1;
            zc[r * 3 + odd] = odd ? vz[q][0] : vz[q][3];  // elem4 / elem3
            if (odd) zc[r * 3 + 2] = vz[q][1];            // elem5
        }
#pragma unroll
        for (int q = 0; q < 3; ++q)
            as2[q * NTHREADS + t] = va[q];
    };

    auto computeT = [&](int tile) {
        size_t rowBase = (size_t)tile * ROWS_PER_BLOCK;
#pragma unroll
        for (int k = 0; k < 2; ++k) {
            int r = k * NTHREADS + t;
            float c0 = zc[r * 3 + 0];
            float c1 = zc[r * 3 + 1];
            float c2 = zc[r * 3 + 2];
            const float* ar = &as_[r * 3];
            float val = ar[0];
            float m = c0;
            if (c1 > m) { m = c1; val = ar[1]; }  // strict > => first-max
            if (c2 > m) {          val = ar[2]; }
            __builtin_nontemporal_store(val, &out[rowBase + r]);
        }
    };

    int tile = blockIdx.x;
    if (tile >= ntiles) return;
    loadT(vzA, vaA, tile);

    for (;;) {
        // --- phase A: prefetch B, stage+compute A ---
        int tB = tile + G;
        if (tB < ntiles) loadT(vzB, vaB, tB);
        __syncthreads();          // prior tile's LDS reads done
        writeLds(vzA, vaA);
        __syncthreads();
        computeT(tile);
        if (tB >= ntiles) break;
        tile = tB;

        // --- phase B: prefetch A, stage+compute B ---
        int tA = tile + G;
        if (tA < ntiles) loadT(vzA, vaA, tA);
        __syncthreads();
        writeLds(vzB, vaB);
        __syncthreads();
        computeT(tile);
        if (tA >= ntiles) break;
        tile = tA;
    }
}

// generic tail (unused for B=4194304, kept for safety)
__global__ void color_val_tail(
    const float* __restrict__ z,
    const float* __restrict__ a,
    float* __restrict__ out,
    size_t start, size_t B)
{
    size_t i = start + blockIdx.x * blockDim.x + threadIdx.x;
    if (i >= B) return;
    float c0 = z[i * 8 + 3], c1 = z[i * 8 + 4], c2 = z[i * 8 + 5];
    float val = a[i * 3 + 0];
    float m = c0;
    if (c1 > m) { m = c1; val = a[i * 3 + 1]; }
    if (c2 > m) {          val = a[i * 3 + 2]; }
    out[i] = val;
}

extern "C" void kernel_launch(void* const* d_in, const int* in_sizes, int n_in,
                              void* d_out, int out_size, void* d_ws, size_t ws_size,
                              hipStream_t stream) {
    const float* z = (const float*)d_in[0];  // (B, 8) f32
    const float* a = (const float*)d_in[1];  // (B, 3) f32
    float* out = (float*)d_out;              // (B,)  f32

    size_t B = (size_t)out_size;             // 4194304
    size_t ntiles = B / ROWS_PER_BLOCK;      // 8192
    size_t rem = B % ROWS_PER_BLOCK;         // 0

    if (ntiles > 0) {
        int grid = (int)(ntiles < NBLOCKS ? ntiles : NBLOCKS);
        color_val_pipe<<<grid, NTHREADS, 0, stream>>>(z, a, out, (int)ntiles);
    }
    if (rem > 0) {
        size_t start = ntiles * ROWS_PER_BLOCK;
        int blocks = (int)((rem + 255) / 256);
        color_val_tail<<<blocks, 256, 0, stream>>>(z, a, out, start, B);
    }
}

// Round 7
// 34.286 us; speedup vs baseline: 1.0886x; 1.0886x over previous
//
#include <hip/hip_runtime.h>
#include <hip/hip_bf16.h>

// out[i] = a[i, argmax_j(z[i, 3+j])], j in {0,1,2}, first-max tie-break.
// B = 4194304 rows; z row = 8 f32 (32B), a row = 3 f32 (12B).
//
// One-shot, 1024 rows/block, ALL global accesses are float4 AND
// lane-contiguous (1024B per wave instruction):
//   z:   8 x float4/thread -> LDS (colors only, 12 KB)
//   a:   3 x float4/thread -> LDS (12 KB)
//   out: 1 x float4/thread (thread t computes rows 4t..4t+3)

#define ROWS_PER_BLOCK 1024
#define NTHREADS 256

typedef float nfloat4 __attribute__((ext_vector_type(4)));

__global__ __launch_bounds__(NTHREADS) void color_val_w4(
    const float* __restrict__ z,
    const float* __restrict__ a,
    float* __restrict__ out)
{
    __shared__ float zc[ROWS_PER_BLOCK * 3];                 // 12 KB colors
    __shared__ __align__(16) float as_[ROWS_PER_BLOCK * 3];  // 12 KB
    nfloat4* as4 = reinterpret_cast<nfloat4*>(as_);

    const int t = threadIdx.x;
    const size_t rowBase = (size_t)blockIdx.x * ROWS_PER_BLOCK;

    // ---- stage z colors: 2048 contiguous float4 loads per block ----
    // float4 f covers row r=f>>1; even f = elems 0-3 (need [3]),
    // odd f = elems 4-7 (need [0]=elem4, [1]=elem5).
    const nfloat4* zg = reinterpret_cast<const nfloat4*>(z) + rowBase * 2;
#pragma unroll
    for (int q = 0; q < 8; ++q) {
        int f = q * NTHREADS + t;
        nfloat4 v = __builtin_nontemporal_load(&zg[f]);
        int r = f >> 1;
        int odd = f & 1;
        zc[r * 3 + odd] = odd ? v[0] : v[3];   // elem4 (odd) / elem3 (even)
        if (odd) zc[r * 3 + 2] = v[1];         // elem5
    }

    // ---- stage a: 768 contiguous float4 loads per block ----
    const nfloat4* ag = reinterpret_cast<const nfloat4*>(a) + (rowBase * 3) / 4;
#pragma unroll
    for (int q = 0; q < 3; ++q) {
        int p4 = q * NTHREADS + t;
        as4[p4] = __builtin_nontemporal_load(&ag[p4]);
    }

    __syncthreads();

    // ---- compute: thread t handles rows 4t..4t+3, one float4 store ----
    nfloat4 o;
#pragma unroll
    for (int k = 0; k < 4; ++k) {
        int r = 4 * t + k;
        float c0 = zc[r * 3 + 0];
        float c1 = zc[r * 3 + 1];
        float c2 = zc[r * 3 + 2];
        const float* ar = &as_[r * 3];
        float val = ar[0];
        float m = c0;
        if (c1 > m) { m = c1; val = ar[1]; }   // strict > => first-max
        if (c2 > m) {          val = ar[2]; }
        o[k] = val;
    }
    nfloat4* og = reinterpret_cast<nfloat4*>(out) + rowBase / 4;
    __builtin_nontemporal_store(o, &og[t]);    // 1024B per wave instr

}

// generic tail (unused for B=4194304, kept for safety)
__global__ void color_val_tail(
    const float* __restrict__ z,
    const float* __restrict__ a,
    float* __restrict__ out,
    size_t start, size_t B)
{
    size_t i = start + blockIdx.x * blockDim.x + threadIdx.x;
    if (i >= B) return;
    float c0 = z[i * 8 + 3], c1 = z[i * 8 + 4], c2 = z[i * 8 + 5];
    float val = a[i * 3 + 0];
    float m = c0;
    if (c1 > m) { m = c1; val = a[i * 3 + 1]; }
    if (c2 > m) {          val = a[i * 3 + 2]; }
    out[i] = val;
}

extern "C" void kernel_launch(void* const* d_in, const int* in_sizes, int n_in,
                              void* d_out, int out_size, void* d_ws, size_t ws_size,
                              hipStream_t stream) {
    const float* z = (const float*)d_in[0];  // (B, 8) f32
    const float* a = (const float*)d_in[1];  // (B, 3) f32
    float* out = (float*)d_out;              // (B,)  f32

    size_t B = (size_t)out_size;             // 4194304
    size_t nfull = B / ROWS_PER_BLOCK;       // 4096
    size_t rem = B % ROWS_PER_BLOCK;         // 0

    if (nfull > 0)
        color_val_w4<<<(int)nfull, NTHREADS, 0, stream>>>(z, a, out);
    if (rem > 0) {
        size_t start = nfull * ROWS_PER_BLOCK;
        int blocks = (int)((rem + 255) / 256);
        color_val_tail<<<blocks, 256, 0, stream>>>(z, a, out, start, B);
    }
}